// Round 9
// baseline (329.480 us; speedup 1.0000x reference)
//
#include <hip/hip_runtime.h>
#include <hip/hip_bf16.h>
#include <hip/hip_fp16.h>

#define B_ 8
#define N_ 10000
#define E_ 160000
#define D_ 256
#define H_ 128
#define SLOPE 0.2f
#define NCHUNK 50   // node chunks for dense weighted sum (200 nodes/chunk)

// edge-sort config
#define NB_ 64            // histogram/scatter blocks
#define EPB_ (E_ / NB_)   // 2500 edges per block
#define BINS_ 256         // 16 dst-buckets x 16 src-buckets
#define NPB_ (N_ / 16)    // 625 nodes per bucket

// softmax stats config
#define SB_ 64            // stat blocks
#define SEB_ (E_ / SB_)   // 2500 edges per stat block

typedef __attribute__((ext_vector_type(8))) _Float16 v8h;
typedef __attribute__((ext_vector_type(4))) _Float16 v4h;
typedef __attribute__((ext_vector_type(2))) _Float16 v2h;
typedef __attribute__((ext_vector_type(4))) float f32x4;

static __device__ __forceinline__ float dot2f(v2h a, v2h b, float c) {
#if __has_builtin(__builtin_amdgcn_fdot2)
    return __builtin_amdgcn_fdot2(a, b, c, false);
#else
    return fmaf((float)a.y, (float)b.y, fmaf((float)a.x, (float)b.x, c));
#endif
}

// ---------------------------------------------------------------- K-detect
__global__ __launch_bounds__(64) void k_detect(const int* __restrict__ eidx_raw,
                                               const unsigned int* __restrict__ mask32,
                                               int* __restrict__ flags) {
    const int t = threadIdx.x;
    unsigned long long oddnz = __ballot(eidx_raw[2 * t + 1] != 0);
    unsigned long long mgt1  = __ballot(mask32[t] > 1u);
    if (t == 0) {
        flags[0] = (oddnz == 0ull) ? 1 : 0;  // edge_index is int64
        flags[1] = (mgt1 != 0ull) ? 1 : 0;   // mask is 1-byte bool
    }
}

// ---------------------------------------------------------------- K-canon (+ kW merged)
__global__ __launch_bounds__(256) void k_canon(const int* __restrict__ eidx_raw,
                                               const unsigned char* __restrict__ mask8,
                                               const unsigned int* __restrict__ mask32,
                                               const int* __restrict__ flags,
                                               const float* __restrict__ W1,
                                               const float* __restrict__ b1,
                                               const float* __restrict__ W2,
                                               int* __restrict__ ce,
                                               unsigned char* __restrict__ cm,
                                               unsigned char* __restrict__ cmT,
                                               __half* __restrict__ Wt,
                                               __half* __restrict__ b1h,
                                               __half* __restrict__ w2h) {
    const int i = blockIdx.x * 256 + threadIdx.x;
    const int f_e = flags[0], f_m = flags[1];
    if (i < 2 * E_) ce[i] = f_e ? eidx_raw[2 * i] : eidx_raw[i];
    if (i < B_ * N_) {
        unsigned char v = f_m ? (unsigned char)(mask8[i] != 0)
                              : (unsigned char)(mask32[i] != 0u);
        cm[i] = v;
        const int b = i / N_;
        const int n = i - b * N_;
        cmT[n * 8 + b] = v;
    }
    if (i < 2 * 256 * 128) {  // W1 -> fp16 transposed
        const int f = i & 127;
        const int row = i >> 7;       // 0..511
        const int c = row >> 8, k = row & 255;
        Wt[((c * 128 + f) * 256) + k] = __float2half(W1[row * 128 + f]);
    }
    if (i < 128) {
        b1h[i] = __float2half(b1[i]);
        w2h[i] = __float2half(W2[i]);
    }
}

// ---------------------------------------------------------------- khist (+ mask count merged)
__global__ __launch_bounds__(256) void khist(const int* __restrict__ ce,
                                             const unsigned char* __restrict__ cm,
                                             int* __restrict__ hpart,
                                             float* __restrict__ cnt) {
    const int tid = threadIdx.x;
    if (blockIdx.x < NB_) {
        __shared__ int h[BINS_];
        h[tid] = 0;
        __syncthreads();
        const int base = blockIdx.x * EPB_;
        for (int i = tid; i < EPB_; i += 256) {
            const int s = ce[base + i], d = ce[E_ + base + i];
            const int bin = (d / NPB_) * 16 + s / NPB_;
            atomicAdd(&h[bin], 1);
        }
        __syncthreads();
        hpart[blockIdx.x * BINS_ + tid] = h[tid];
    } else {
        const int b = blockIdx.x - NB_;
        int c = 0;
        for (int i = tid; i < N_; i += 256) c += cm[b * N_ + i] ? 1 : 0;
        __shared__ int red[256];
        red[tid] = c;
        __syncthreads();
        for (int s = 128; s > 0; s >>= 1) {
            if (tid < s) red[tid] += red[tid + s];
            __syncthreads();
        }
        if (tid == 0) cnt[b] = (float)red[0];
    }
}

// ---------------------------------------------------------------- edge sort: prefix (+ bucket starts)
__global__ __launch_bounds__(256) void kprefix(const int* __restrict__ hpart,
                                               int* __restrict__ offsetG,
                                               int* __restrict__ bstart) {
    __shared__ int cnt[BINS_];
    __shared__ int excl[BINS_];
    const int bin = threadIdx.x;
    int c = 0;
    for (int b = 0; b < NB_; b++) c += hpart[b * BINS_ + bin];
    cnt[bin] = c;
    __syncthreads();
    if (bin == 0) {
        int r = 0;
        for (int i = 0; i < BINS_; i++) { excl[i] = r; r += cnt[i]; }
    }
    __syncthreads();
    if ((bin & 15) == 0) bstart[bin >> 4] = excl[bin];
    if (bin == 0) bstart[16] = E_;
    int run = excl[bin];
    for (int b = 0; b < NB_; b++) {
        offsetG[b * BINS_ + bin] = run;
        run += hpart[b * BINS_ + bin];
    }
}

// ---------------------------------------------------------------- edge sort: scatter (packed records + rank)
__global__ __launch_bounds__(256) void kscatter(const int* __restrict__ ce,
                                                const int* __restrict__ offsetG,
                                                int4* __restrict__ esort,
                                                int* __restrict__ rank) {
    __shared__ int loc[BINS_];
    const int tid = threadIdx.x;
    loc[tid] = offsetG[blockIdx.x * BINS_ + tid];
    __syncthreads();
    const int base = blockIdx.x * EPB_;
    for (int i = tid; i < EPB_; i += 256) {
        const int e = base + i;
        const int s = ce[e], d = ce[E_ + e];
        const int bin = (d / NPB_) * 16 + s / NPB_;
        const int pos = atomicAdd(&loc[bin], 1);
        esort[pos] = make_int4(s, d, e, 0);
        rank[e] = pos;
    }
}

// ---------------------------------------------------------------- K1: MFMA projection GEMM — no LDS, no barriers
// 64-row tiles, grid 1250. B-fragments loaded straight from global X
// (16 rows x 64B per instruction — same coalescing as staged path); W
// fragments from L2-hot Wt. Zero __syncthreads => compiler pipelines freely.
__global__ __launch_bounds__(256) void k1_mfma(const float* __restrict__ X,
                                               const __half* __restrict__ Wt,
                                               __half* __restrict__ ps,
                                               __half* __restrict__ pd) {
    const int rb = blockIdx.x;   // 0..1249
    const int tid = threadIdx.x;
    const int wave = tid >> 6, lane = tid & 63;
    const int quad = lane >> 4, l16 = lane & 15;

    f32x4 acc[2][2][4];  // [cb][ft][nt]
#pragma unroll
    for (int c = 0; c < 2; c++)
#pragma unroll
        for (int i = 0; i < 2; i++)
#pragma unroll
            for (int j = 0; j < 4; j++) acc[c][i][j] = (f32x4){0.f, 0.f, 0.f, 0.f};

    const int row_base = rb * 64;
    const __half* wbase = Wt + ((size_t)(wave * 32 + l16)) * 256 + quad * 8;

    for (int kc = 0; kc < 8; ++kc) {
        v8h wf[2][2];
#pragma unroll
        for (int cb = 0; cb < 2; ++cb)
#pragma unroll
            for (int ft = 0; ft < 2; ++ft)
                wf[cb][ft] = *(const v8h*)(wbase + ((size_t)cb * 128 + ft * 16) * 256 + kc * 32);

#pragma unroll
        for (int nt = 0; nt < 4; ++nt) {
            const float* xp = &X[(size_t)(row_base + nt * 16 + l16) * 256 + kc * 32 + quad * 8];
            float4 x0 = *(const float4*)xp;
            float4 x1 = *(const float4*)(xp + 4);
            v8h xf = {(_Float16)x0.x, (_Float16)x0.y, (_Float16)x0.z, (_Float16)x0.w,
                      (_Float16)x1.x, (_Float16)x1.y, (_Float16)x1.z, (_Float16)x1.w};
            acc[0][0][nt] = __builtin_amdgcn_mfma_f32_16x16x32_f16(wf[0][0], xf, acc[0][0][nt], 0, 0, 0);
            acc[0][1][nt] = __builtin_amdgcn_mfma_f32_16x16x32_f16(wf[0][1], xf, acc[0][1][nt], 0, 0, 0);
            acc[1][0][nt] = __builtin_amdgcn_mfma_f32_16x16x32_f16(wf[1][0], xf, acc[1][0][nt], 0, 0, 0);
            acc[1][1][nt] = __builtin_amdgcn_mfma_f32_16x16x32_f16(wf[1][1], xf, acc[1][1][nt], 0, 0, 0);
        }
    }

#pragma unroll
    for (int nt = 0; nt < 4; ++nt) {
        const int R = row_base + nt * 16 + l16;
        const int b = R / N_;
        const int n = R - b * N_;
        const size_t off = ((size_t)(n * 8 + b)) * 128 + wave * 32 + quad * 4;
#pragma unroll
        for (int cb = 0; cb < 2; ++cb) {
            __half* base = (cb ? pd : ps) + off;
#pragma unroll
            for (int ft = 0; ft < 2; ++ft) {
                f32x4 a = acc[cb][ft][nt];
                v4h h = {(_Float16)a.x, (_Float16)a.y, (_Float16)a.z, (_Float16)a.w};
                *(v4h*)(base + ft * 16) = h;
            }
        }
    }
}

// ---------------------------------------------------------------- K2: edge scores, 2 edges/wave -> scS[pos][8]
__global__ __launch_bounds__(256) void k2_scores(const __half* __restrict__ ps,
                                                 const __half* __restrict__ pd,
                                                 const int4* __restrict__ esort,
                                                 const __half* __restrict__ b1h,
                                                 const __half* __restrict__ w2h,
                                                 const float* __restrict__ b2,
                                                 const float* __restrict__ eattr,
                                                 float* __restrict__ scS) {
    const int tid = threadIdx.x;
    const int wave = tid >> 6;
    const int lane = tid & 63;
    const int bid = blockIdx.x;                    // 0..19999
    const int lb = (bid & 7) * 2500 + (bid >> 3);  // XCD swizzle
    const int e0 = lb * 8 + wave * 2;

    const int b = lane >> 3;
    const int hi = (lane & 7) * 16;

    v2h b1p[8], w2p[8];
    {
        const v2h* bp = (const v2h*)(b1h + hi);
        const v2h* wp = (const v2h*)(w2h + hi);
#pragma unroll
        for (int j = 0; j < 8; j++) { b1p[j] = bp[j]; w2p[j] = wp[j]; }
    }
    const float bias2 = b2[0];
    const v2h slp = {(_Float16)SLOPE, (_Float16)SLOPE};

#pragma unroll
    for (int q = 0; q < 2; q++) {
        const int e = e0 + q;
        const int4 er = esort[e];
        const int src = er.x, dst = er.y, orig = er.z;

        const float4* aps = (const float4*)&ps[((size_t)src * 8 + b) * 128 + hi];
        const float4* apd = (const float4*)&pd[((size_t)dst * 8 + b) * 128 + hi];
        float4 rs[2] = {aps[0], aps[1]};
        float4 rd[2] = {apd[0], apd[1]};
        const v2h* sv = (const v2h*)rs;
        const v2h* dv = (const v2h*)rd;

        float acc = 0.f;
#pragma unroll
        for (int j = 0; j < 8; j++) {
            v2h x = sv[j] + dv[j] + b1p[j];
            v2h l = __builtin_elementwise_max(x, x * slp);   // LeakyReLU, slope<1
            acc = dot2f(l, w2p[j], acc);
        }
        acc += __shfl_xor(acc, 1);
        acc += __shfl_xor(acc, 2);
        acc += __shfl_xor(acc, 4);

        if ((lane & 7) == 0) {
            scS[(size_t)e * 8 + b] = (acc + bias2) * eattr[orig];
        }
    }
}

// ---------------------------------------------------------------- K3s: per-chunk per-batch (max, shifted exp-sum)
__global__ __launch_bounds__(256) void k3s_stats(const float* __restrict__ scS,
                                                 float* __restrict__ pmax,
                                                 double* __restrict__ psum) {
    const int tid = threadIdx.x;
    const int wave = tid >> 6, lane = tid & 63;
    const int base = blockIdx.x * SEB_;

    float fm[8];
#pragma unroll
    for (int j = 0; j < 8; j++) fm[j] = -3.4e38f;
    for (int i = tid; i < SEB_; i += 256) {
        const float4* s4 = (const float4*)&scS[(size_t)(base + i) * 8];
        float4 a = s4[0], b = s4[1];
        fm[0] = fmaxf(fm[0], a.x); fm[1] = fmaxf(fm[1], a.y);
        fm[2] = fmaxf(fm[2], a.z); fm[3] = fmaxf(fm[3], a.w);
        fm[4] = fmaxf(fm[4], b.x); fm[5] = fmaxf(fm[5], b.y);
        fm[6] = fmaxf(fm[6], b.z); fm[7] = fmaxf(fm[7], b.w);
    }
#pragma unroll
    for (int k = 1; k <= 32; k <<= 1)
#pragma unroll
        for (int j = 0; j < 8; j++) fm[j] = fmaxf(fm[j], __shfl_xor(fm[j], k));
    __shared__ float lmax[4][8];
    if (lane == 0)
#pragma unroll
        for (int j = 0; j < 8; j++) lmax[wave][j] = fm[j];
    __syncthreads();
    float m[8];
#pragma unroll
    for (int j = 0; j < 8; j++)
        m[j] = fmaxf(fmaxf(lmax[0][j], lmax[1][j]), fmaxf(lmax[2][j], lmax[3][j]));

    double s[8];
#pragma unroll
    for (int j = 0; j < 8; j++) s[j] = 0.0;
    for (int i = tid; i < SEB_; i += 256) {
        const float4* s4 = (const float4*)&scS[(size_t)(base + i) * 8];
        float4 a = s4[0], b = s4[1];
        s[0] += (double)expf(a.x - m[0]); s[1] += (double)expf(a.y - m[1]);
        s[2] += (double)expf(a.z - m[2]); s[3] += (double)expf(a.w - m[3]);
        s[4] += (double)expf(b.x - m[4]); s[5] += (double)expf(b.y - m[5]);
        s[6] += (double)expf(b.z - m[6]); s[7] += (double)expf(b.w - m[7]);
    }
#pragma unroll
    for (int k = 1; k <= 32; k <<= 1)
#pragma unroll
        for (int j = 0; j < 8; j++) s[j] += __shfl_xor(s[j], k);
    __shared__ double lsum[4][8];
    if (lane == 0)
#pragma unroll
        for (int j = 0; j < 8; j++) lsum[wave][j] = s[j];
    __syncthreads();
    if (tid < 8) {
        pmax[blockIdx.x * 8 + tid] = m[tid];
        psum[blockIdx.x * 8 + tid] = lsum[0][tid] + lsum[1][tid] + lsum[2][tid] + lsum[3][tid];
    }
}

// stats prologue: reduce 64 chunk (m_c,l_c) -> shared m[8], inv[8]. Call from wave 0.
static __device__ __forceinline__ void stats_combine(const float* __restrict__ pmax,
                                                     const double* __restrict__ psum,
                                                     int tid, float* smx, float* sinvx) {
    if (tid < 64) {
        float v[8];
        const float4* p4 = (const float4*)&pmax[tid * 8];
        float4 a = p4[0], b = p4[1];
        v[0] = a.x; v[1] = a.y; v[2] = a.z; v[3] = a.w;
        v[4] = b.x; v[5] = b.y; v[6] = b.z; v[7] = b.w;
        float mc[8];
#pragma unroll
        for (int j = 0; j < 8; j++) mc[j] = v[j];
#pragma unroll
        for (int k = 1; k <= 32; k <<= 1)
#pragma unroll
            for (int j = 0; j < 8; j++) v[j] = fmaxf(v[j], __shfl_xor(v[j], k));
        double z[8];
#pragma unroll
        for (int j = 0; j < 8; j++)
            z[j] = psum[tid * 8 + j] * (double)expf(mc[j] - v[j]);
#pragma unroll
        for (int k = 1; k <= 32; k <<= 1)
#pragma unroll
            for (int j = 0; j < 8; j++) z[j] += __shfl_xor(z[j], k);
        if (tid == 0)
#pragma unroll
            for (int j = 0; j < 8; j++) { smx[j] = v[j]; sinvx[j] = (float)(1.0 / z[j]); }
    }
}

// ---------------------------------------------------------------- K3e: normalize -> wout (coalesced)
__global__ __launch_bounds__(256) void k3e_norm(const float* __restrict__ scS,
                                                const int* __restrict__ rank,
                                                const float* __restrict__ pmax,
                                                const double* __restrict__ psum,
                                                float* __restrict__ wout) {
    const int tid = threadIdx.x;
    __shared__ float smx[8], sinvx[8];
    stats_combine(pmax, psum, tid, smx, sinvx);
    __syncthreads();

    const int e = blockIdx.x * 256 + tid;
    const int p = rank[e];
    const float4* s4 = (const float4*)&scS[(size_t)p * 8];
    float4 a = s4[0], b = s4[1];
    float wv[8];
    wv[0] = expf(a.x - smx[0]) * sinvx[0]; wv[1] = expf(a.y - smx[1]) * sinvx[1];
    wv[2] = expf(a.z - smx[2]) * sinvx[2]; wv[3] = expf(a.w - smx[3]) * sinvx[3];
    wv[4] = expf(b.x - smx[4]) * sinvx[4]; wv[5] = expf(b.y - smx[5]) * sinvx[5];
    wv[6] = expf(b.z - smx[6]) * sinvx[6]; wv[7] = expf(b.w - smx[7]) * sinvx[7];
#pragma unroll
    for (int j = 0; j < 8; j++) wout[(size_t)j * E_ + e] = wv[j];   // coalesced
}

// ---------------------------------------------------------------- K3f: bucket-aligned node-weight binning
__global__ __launch_bounds__(256) void k3f_bin(const int4* __restrict__ esort,
                                               const float* __restrict__ scS,
                                               const unsigned char* __restrict__ cmT,
                                               const float* __restrict__ pmax,
                                               const double* __restrict__ psum,
                                               const int* __restrict__ bstart,
                                               float* __restrict__ Wpf,
                                               float* __restrict__ Wpm) {
    const int bucket = blockIdx.x;  // 0..15
    const int sub = blockIdx.y;     // 0..7
    const int tid = threadIdx.x;

    __shared__ float smx[8], sinvx[8];
    stats_combine(pmax, psum, tid, smx, sinvx);

    __shared__ float lWf[NPB_ * 8];   // 20 KB
    __shared__ float lWm[NPB_ * 8];   // 20 KB
    for (int i = tid; i < NPB_ * 8; i += 256) { lWf[i] = 0.f; lWm[i] = 0.f; }
    __syncthreads();

    float m[8], inv[8];
#pragma unroll
    for (int j = 0; j < 8; j++) { m[j] = smx[j]; inv[j] = sinvx[j]; }

    const int bs = bstart[bucket], be = bstart[bucket + 1];
    const int len = be - bs;
    const int s0 = bs + (int)((long long)len * sub / 8);
    const int s1 = bs + (int)((long long)len * (sub + 1) / 8);
    const int nbase = bucket * NPB_;

    for (int p = s0 + tid; p < s1; p += 256) {
        const int4 er = esort[p];
        const int src = er.x;
        const int rel = er.y - nbase;
        const float4* s4 = (const float4*)&scS[(size_t)p * 8];
        float4 a = s4[0], b = s4[1];
        float wv[8];
        wv[0] = expf(a.x - m[0]) * inv[0]; wv[1] = expf(a.y - m[1]) * inv[1];
        wv[2] = expf(a.z - m[2]) * inv[2]; wv[3] = expf(a.w - m[3]) * inv[3];
        wv[4] = expf(b.x - m[4]) * inv[4]; wv[5] = expf(b.y - m[5]) * inv[5];
        wv[6] = expf(b.z - m[6]) * inv[6]; wv[7] = expf(b.w - m[7]) * inv[7];
        const unsigned long long mm = *(const unsigned long long*)&cmT[src * 8];
        float* lf = &lWf[rel * 8];
        float* lm = &lWm[rel * 8];
#pragma unroll
        for (int j = 0; j < 8; j++) {
            atomicAdd(&lf[j], wv[j]);
            if ((mm >> (8 * j)) & 1ull) atomicAdd(&lm[j], wv[j]);
        }
    }
    __syncthreads();

    float* of = Wpf + ((size_t)bucket * 8 + sub) * (NPB_ * 8);
    float* om = Wpm + ((size_t)bucket * 8 + sub) * (NPB_ * 8);
    for (int i = tid; i < NPB_ * 8; i += 256) { of[i] = lWf[i]; om[i] = lWm[i]; }
}

// ---------------------------------------------------------------- K3g: reduce 8 sub-partials -> WfT/WmT [n][8]
__global__ __launch_bounds__(256) void k3g_reduce(const float* __restrict__ Wpf,
                                                  const float* __restrict__ Wpm,
                                                  float* __restrict__ WfT,
                                                  float* __restrict__ WmT) {
    const int i = blockIdx.x * 256 + threadIdx.x;  // < N_*8
    if (i >= N_ * 8) return;
    const int n = i >> 3, b = i & 7;
    const int bucket = n / NPB_;
    const int rel = n - bucket * NPB_;
    float sf = 0.f, sm = 0.f;
#pragma unroll
    for (int sub = 0; sub < 8; sub++) {
        const size_t off = ((size_t)bucket * 8 + sub) * (NPB_ * 8) + rel * 8 + b;
        sf += Wpf[off];
        sm += Wpm[off];
    }
    WfT[i] = sf;
    WmT[i] = sm;
}

// ---------------------------------------------------------------- K4b: dense weighted sum over X
__global__ __launch_bounds__(256) void k4b_wsum(const float* __restrict__ X,
                                                const float* __restrict__ WmT,
                                                const float* __restrict__ WfT,
                                                float* __restrict__ gpart) {
    const int c = blockIdx.x;
    const int b = blockIdx.y;
    const int tx = threadIdx.x & 63;
    const int ty = threadIdx.x >> 6;
    const int npc = N_ / NCHUNK;
    const int n0 = c * npc;

    const float4* X4 = (const float4*)(X + (size_t)b * N_ * 256);
    float4 am = {0.f, 0.f, 0.f, 0.f};
    float4 af = {0.f, 0.f, 0.f, 0.f};

    for (int n = n0 + ty; n < n0 + npc; n += 4) {
        float wm = WmT[n * 8 + b];
        float wf = WfT[n * 8 + b];
        float4 v = X4[(size_t)n * 64 + tx];
        am.x = fmaf(wm, v.x, am.x); am.y = fmaf(wm, v.y, am.y);
        am.z = fmaf(wm, v.z, am.z); am.w = fmaf(wm, v.w, am.w);
        af.x = fmaf(wf, v.x, af.x); af.y = fmaf(wf, v.y, af.y);
        af.z = fmaf(wf, v.z, af.z); af.w = fmaf(wf, v.w, af.w);
    }

    __shared__ float4 red[256];
    red[threadIdx.x] = am;
    __syncthreads();
    if (ty == 0) {
        float4 r1 = red[tx + 64], r2 = red[tx + 128], r3 = red[tx + 192];
        am.x += r1.x + r2.x + r3.x; am.y += r1.y + r2.y + r3.y;
        am.z += r1.z + r2.z + r3.z; am.w += r1.w + r2.w + r3.w;
    }
    __syncthreads();
    red[threadIdx.x] = af;
    __syncthreads();
    if (ty == 0) {
        float4 r1 = red[tx + 64], r2 = red[tx + 128], r3 = red[tx + 192];
        af.x += r1.x + r2.x + r3.x; af.y += r1.y + r2.y + r3.y;
        af.z += r1.z + r2.z + r3.z; af.w += r1.w + r2.w + r3.w;
        float4* gp4 = (float4*)gpart;
        gp4[((c * 2 + 0) * 8 + b) * 64 + tx] = am;
        gp4[((c * 2 + 1) * 8 + b) * 64 + tx] = af;
    }
}

// ---------------------------------------------------------------- K5: finalize
__global__ __launch_bounds__(256) void k5_final(const float* __restrict__ gpart,
                                                const float* __restrict__ cnt,
                                                float* __restrict__ gf) {
    const int b = blockIdx.x;
    const int d = threadIdx.x;
    float sm = 0.f, sf = 0.f;
    for (int c = 0; c < NCHUNK; c++) {
        sm += gpart[((c * 2 + 0) * 8 + b) * 256 + d];
        sf += gpart[((c * 2 + 1) * 8 + b) * 256 + d];
    }
    const float cn = cnt[b];
    gf[b * 256 + d] = (cn > 0.f) ? (sm / cn) : (sf / (float)N_);
}

// ---------------------------------------------------------------- launch
static inline char* align16(char* p) {
    return (char*)(((uintptr_t)p + 15) & ~(uintptr_t)15);
}

extern "C" void kernel_launch(void* const* d_in, const int* in_sizes, int n_in,
                              void* d_out, int out_size, void* d_ws, size_t ws_size,
                              hipStream_t stream) {
    const float* X     = (const float*)d_in[0];
    const float* eattr = (const float*)d_in[1];
    const float* W1    = (const float*)d_in[2];
    const float* b1    = (const float*)d_in[3];
    const float* W2    = (const float*)d_in[4];
    const float* b2    = (const float*)d_in[5];
    const int*   eidx_raw = (const int*)d_in[6];
    const unsigned char* mask8 = (const unsigned char*)d_in[7];
    const unsigned int*  mask32 = (const unsigned int*)d_in[7];

    float* out  = (float*)d_out;
    float* gf   = out;          // [B,D]
    float* wout = out + 2048;   // [B,E]

    // persistent region
    char* cur = (char*)d_ws;
    __half* ps_h = (__half*)cur;             cur += (size_t)N_ * 8 * 128 * 2;   // 20.48 MB
    __half* pd_h = (__half*)cur;             cur += (size_t)N_ * 8 * 128 * 2;
    __half* Wt   = (__half*)cur;             cur += 2 * 128 * 256 * 2;
    int* ce      = (int*)cur;                cur += 2 * E_ * 4;
    unsigned char* cmT = (unsigned char*)cur; cur += N_ * 8;
    unsigned char* cm  = (unsigned char*)cur; cur += B_ * N_;
    cur = align16(cur);
    float* cnt   = (float*)cur;              cur += 8 * 4;
    int* flags   = (int*)cur;                cur += 2 * 4;
    cur = align16(cur);
    float* pmax  = (float*)cur;              cur += SB_ * 8 * 4;
    cur = align16(cur);
    double* psum = (double*)cur;             cur += SB_ * 8 * 8;
    float* gpart = (float*)cur;              cur += NCHUNK * 2 * 8 * 256 * 4;
    int* hpart   = (int*)cur;                cur += NB_ * BINS_ * 4;
    int* offsetG = (int*)cur;                cur += NB_ * BINS_ * 4;
    int* bstart  = (int*)cur;                cur += 32 * 4;
    cur = align16(cur);
    int4* esort  = (int4*)cur;               cur += (size_t)E_ * 16;
    int* rankB   = (int*)cur;                cur += E_ * 4;
    __half* b1h  = (__half*)cur;             cur += 128 * 2;
    __half* w2h  = (__half*)cur;             cur += 128 * 2;
    cur = align16(cur);
    float* scS   = (float*)cur;              cur += (size_t)E_ * 8 * 4;

    // overlay region (reuses ps_h: dead after k2/k3s/k3e... used only by k3f/k3g)
    char* ocur = (char*)d_ws;
    float* Wpf = (float*)ocur;               ocur += (size_t)16 * 8 * NPB_ * 8 * 4;  // 2.56 MB
    float* Wpm = (float*)ocur;               ocur += (size_t)16 * 8 * NPB_ * 8 * 4;
    float* WfT = (float*)ocur;               ocur += N_ * 8 * 4;
    float* WmT = (float*)ocur;               ocur += N_ * 8 * 4;

    hipLaunchKernelGGL(k_detect, dim3(1), dim3(64), 0, stream, eidx_raw, mask32, flags);
    hipLaunchKernelGGL(k_canon, dim3(1250), dim3(256), 0, stream,
                       eidx_raw, mask8, mask32, flags, W1, b1, W2,
                       ce, cm, cmT, Wt, b1h, w2h);
    hipLaunchKernelGGL(khist, dim3(NB_ + 8), dim3(256), 0, stream, ce, cm, hpart, cnt);
    hipLaunchKernelGGL(kprefix, dim3(1), dim3(256), 0, stream, hpart, offsetG, bstart);
    hipLaunchKernelGGL(kscatter, dim3(NB_), dim3(256), 0, stream, ce, offsetG, esort, rankB);
    hipLaunchKernelGGL(k1_mfma, dim3(1250), dim3(256), 0, stream, X, Wt, ps_h, pd_h);
    hipLaunchKernelGGL(k2_scores, dim3(E_ / 8), dim3(256), 0, stream,
                       ps_h, pd_h, esort, b1h, w2h, b2, eattr, scS);
    hipLaunchKernelGGL(k3s_stats, dim3(SB_), dim3(256), 0, stream, scS, pmax, psum);
    hipLaunchKernelGGL(k3e_norm, dim3(E_ / 256), dim3(256), 0, stream,
                       scS, rankB, pmax, psum, wout);
    hipLaunchKernelGGL(k3f_bin, dim3(16, 8), dim3(256), 0, stream,
                       esort, scS, cmT, pmax, psum, bstart, Wpf, Wpm);
    hipLaunchKernelGGL(k3g_reduce, dim3((N_ * 8 + 255) / 256), dim3(256), 0, stream,
                       Wpf, Wpm, WfT, WmT);
    hipLaunchKernelGGL(k4b_wsum, dim3(NCHUNK, 8), dim3(256), 0, stream, X, WmT, WfT, gpart);
    hipLaunchKernelGGL(k5_final, dim3(8), dim3(256), 0, stream, gpart, cnt, gf);
}